// Round 5
// baseline (548.427 us; speedup 1.0000x reference)
//
#include <hip/hip_runtime.h>
#include <hip/hip_bf16.h>
#include <math.h>

// ---------------------------------------------------------------------------
// FeatureAttnNet v5 for MI355X (gfx950)
//
// score[b,f] = Y0 + sum_c cmd[b,c]*Yc, Y = X @ WKfold^T (BN folded; additive
// BN term cancels in softmax). V GEMM fused with softmax weights.
// v5: weights pre-transposed into exact MFMA B-fragment order (WVT/WKFT) ->
// fused_attn streams B via coalesced global_load_dwordx4 from L1/L2 with NO
// LDS staging and NO barriers; waves fully independent (32 rows each).
// Gram (for BN-K variance): X^T X partials (bf16, in d_out scratch), MFMA,
// one 128x1024-thread launch fused with weight transpose + cmd stats.
// ---------------------------------------------------------------------------

typedef float  f32x4   __attribute__((ext_vector_type(4)));
typedef float  f32x16  __attribute__((ext_vector_type(16)));
typedef __bf16 bf16x4  __attribute__((ext_vector_type(4)));
typedef __bf16 bf16x8  __attribute__((ext_vector_type(8)));

#define MFMA16(A, B, C) __builtin_amdgcn_mfma_f32_16x16x32_bf16((A), (B), (C), 0, 0, 0)
#define MFMA32(A, B, C) __builtin_amdgcn_mfma_f32_32x32x16_bf16((A), (B), (C), 0, 0, 0)

#define EPSV 1e-5f

// ---- workspace layout (bytes) ----
#define WS_WVT   0x000000u   // 1 MiB: V weights in B-fragment order
#define WS_WKFT  0x100000u   // 96 KiB: folded K weights in B-fragment order
#define WS_G     0x120000u   // 2*256*256 f32 = 512 KiB
#define WS_CS    0x1A0000u   // 2*256 f32 colsums (zeroed)
#define WS_CMDP  0x1A0800u   // 4*14 f32 cmd partials
#define WS_T     0x1A1800u   // 2048 f32
#define WS_U     0x1A3800u   // 2048 f32

// ---------------------------------------------------------------------------
// setup1 (1024 threads): blk<128 -> gram partials (bf16 -> d_out scratch);
// 128..159 -> WV transpose into fragment order; 160..163 -> cmd stats.
__global__ __launch_bounds__(1024, 1) void setup1(const float* __restrict__ feat,
        const float* __restrict__ hid, const float4* __restrict__ cmd,
        const float* __restrict__ Wvz, const float* __restrict__ Wvh,
        __bf16* __restrict__ WVT, float* __restrict__ CMDP, float* __restrict__ CS,
        __bf16* __restrict__ Gp)
{
    __shared__ __bf16 T[256 * 40];
    __shared__ float sm[16][14];
    const int blk = blockIdx.x;
    const int tid = threadIdx.x;

    if (blk >= 160) {                     // ---- cmd stats: 4 blocks ----
        const int b2 = blk - 160;
        float v[14];
#pragma unroll
        for (int k = 0; k < 14; ++k) v[k] = 0.f;
#pragma unroll
        for (int i = 0; i < 16; ++i) {
            float4 c = cmd[b2 * 16384 + i * 1024 + tid];
            v[0] += c.x;  v[1] += c.y;  v[2] += c.z;  v[3] += c.w;
            v[4] += c.x*c.x; v[5] += c.x*c.y; v[6] += c.x*c.z; v[7] += c.x*c.w;
            v[8] += c.y*c.y; v[9] += c.y*c.z; v[10] += c.y*c.w;
            v[11] += c.z*c.z; v[12] += c.z*c.w; v[13] += c.w*c.w;
        }
#pragma unroll
        for (int k = 0; k < 14; ++k) {
            float s = v[k];
#pragma unroll
            for (int off = 32; off; off >>= 1) s += __shfl_xor(s, off);
            if ((tid & 63) == 0) sm[tid >> 6][k] = s;
        }
        __syncthreads();
        if (tid < 14) {
            float s = 0.f;
#pragma unroll
            for (int w = 0; w < 16; ++w) s += sm[w][tid];
            CMDP[b2 * 14 + tid] = s;
        }
        return;
    }
    if (blk >= 128) {                     // ---- WV transpose: 32 blocks ----
        // dst entry E: 16B chunk at WVT + E*16.  E = ((f*2+nt)*16+ks)*64 + lane
#pragma unroll
        for (int i = 0; i < 2; ++i) {
            int E = (blk - 128) * 1024 + i * 32768 + tid;
            int lane = E & 63, D = E >> 6;
            int ks = D & 15, nt = (D >> 4) & 1, f = D >> 5;
            int n32 = lane & 31, hi = lane >> 5;
            int j = f * 64 + nt * 32 + n32;            // V row 0..2047
            int k = ks * 16 + hi * 8;
            const float* src = (j < 1024) ? (Wvz + (size_t)j * 256 + k)
                                          : (Wvh + (size_t)(j - 1024) * 256 + k);
            float4 x0 = *(const float4*)src;
            float4 x1 = *(const float4*)(src + 4);
            bf16x8 v = { (__bf16)x0.x, (__bf16)x0.y, (__bf16)x0.z, (__bf16)x0.w,
                         (__bf16)x1.x, (__bf16)x1.y, (__bf16)x1.z, (__bf16)x1.w };
            *(bf16x8*)(WVT + (size_t)E * 8) = v;
        }
        return;
    }

    // ---- gram: 128 blocks = 2 mats x 64 chunks x 1024 batch rows ----
    const int mat  = blk >> 6;
    const int chunk = blk & 63;
    const float* X = mat ? hid : feat;
    float* cs = CS + mat * 256;
    const int k0   = chunk * 1024;
    const int wid  = tid >> 6, lane = tid & 63, quad = lane >> 4, l15 = lane & 15;
    const int c    = tid & 255;
    const int t4   = tid >> 8;            // 0..3

    f32x4 acc[16];
#pragma unroll
    for (int nt = 0; nt < 16; ++nt) acc[nt] = (f32x4){0.f, 0.f, 0.f, 0.f};

    float clsum = 0.f;
    for (int it = 0; it < 32; ++it) {
        __syncthreads();
        const int kb = k0 + it * 32;
#pragma unroll
        for (int i = 0; i < 8; ++i) {
            int k = t4 + 4 * i;
            float x = X[(size_t)(kb + k) * 256 + c];
            clsum += x;
            T[c * 40 + k] = (__bf16)x;
        }
        __syncthreads();
        bf16x8 a0 = *(const bf16x8*)&T[(wid * 16 + l15) * 40 + quad * 8];
#pragma unroll
        for (int nt = 0; nt < 16; ++nt) {
            bf16x8 b = *(const bf16x8*)&T[(nt * 16 + l15) * 40 + quad * 8];
            acc[nt] = MFMA16(a0, b, acc[nt]);
        }
    }
    atomicAdd(&cs[c], clsum);
    __bf16* outp = Gp + (size_t)blk * 65536;
#pragma unroll
    for (int nt = 0; nt < 16; ++nt)
#pragma unroll
        for (int r = 0; r < 4; ++r) {
            int gi = wid * 16 + quad * 4 + r;
            int gj = nt * 16 + l15;
            outp[gi * 256 + gj] = (__bf16)acc[nt][r];
        }
}

// ---------------------------------------------------------------------------
__global__ void gram_reduce(const __bf16* __restrict__ Gp, float* __restrict__ G)
{
    int o = blockIdx.x * 256 + threadIdx.x;      // 512 x 256 = 131072
    int mat = o >> 16, e = o & 65535;
    const __bf16* p = Gp + (size_t)mat * 64 * 65536 + e;
    float s = 0.f;
#pragma unroll 8
    for (int c = 0; c < 64; ++c) s += (float)p[(size_t)c * 65536];
    G[o] = s;
}

// ---------------------------------------------------------------------------
__global__ void rowstats(const float* __restrict__ Wkz, const float* __restrict__ Wkh,
        const float* __restrict__ G, const float* __restrict__ CS,
        float* __restrict__ Tout, float* __restrict__ Uout)
{
    const int blk = blockIdx.x;               // 256 blocks
    const int mat = blk >> 7, jg = blk & 127;
    const float* Wsrc = (mat ? Wkh : Wkz) + (size_t)jg * 8 * 256;
    const float* Gm = G + (size_t)mat * 65536;
    const float* cs = CS + mat * 256;
    __shared__ float wlT[256 * 8];
    __shared__ float red[4][16];
    const int tid = threadIdx.x, wid = tid >> 6, lane = tid & 63;
#pragma unroll
    for (int jj = 0; jj < 8; ++jj) wlT[tid * 8 + jj] = Wsrc[jj * 256 + tid];
    __syncthreads();
    float inner[8];
#pragma unroll
    for (int jj = 0; jj < 8; ++jj) inner[jj] = 0.f;
    for (int r = 0; r < 256; ++r) {
        float g = Gm[r * 256 + tid];
        float4 w0 = *(const float4*)&wlT[r * 8];
        float4 w1 = *(const float4*)&wlT[r * 8 + 4];
        inner[0] = fmaf(w0.x, g, inner[0]); inner[1] = fmaf(w0.y, g, inner[1]);
        inner[2] = fmaf(w0.z, g, inner[2]); inner[3] = fmaf(w0.w, g, inner[3]);
        inner[4] = fmaf(w1.x, g, inner[4]); inner[5] = fmaf(w1.y, g, inner[5]);
        inner[6] = fmaf(w1.z, g, inner[6]); inner[7] = fmaf(w1.w, g, inner[7]);
    }
    float cst = cs[tid];
#pragma unroll
    for (int jj = 0; jj < 8; ++jj) {
        float wme = wlT[tid * 8 + jj];
        float p = wme * inner[jj];
        float u = wme * cst;
#pragma unroll
        for (int off = 32; off; off >>= 1) { p += __shfl_xor(p, off); u += __shfl_xor(u, off); }
        if (lane == 0) { red[wid][jj] = p; red[wid][jj + 8] = u; }
    }
    __syncthreads();
    if (tid < 16) {
        float s = red[0][tid] + red[1][tid] + red[2][tid] + red[3][tid];
        int jj = tid & 7;
        int j = mat * 1024 + jg * 8 + jj;
        if (tid < 8) Tout[j] = s; else Uout[j] = s;
    }
}

// ---------------------------------------------------------------------------
// foldK2: finalize (BN constants, recomputed per block) + fold + write WKFT
// in B-fragment order.  192 blocks x 256 thr: blk -> (h, rr), tid = k.
__global__ __launch_bounds__(256) void foldK2(const float* __restrict__ Wkz,
        const float* __restrict__ Wkh, const float* __restrict__ Wq,
        const float* __restrict__ gQ, const float* __restrict__ bQ,
        const float* __restrict__ gK, const float* __restrict__ bK,
        const float* __restrict__ CMDP, const float* __restrict__ T,
        const float* __restrict__ U, __bf16* __restrict__ WKFT)
{
    __shared__ float s14[14];
    __shared__ float C0l[64];
    __shared__ float W2l[256];
    const int tid = threadIdx.x;
    if (tid < 14) s14[tid] = CMDP[tid] + CMDP[14 + tid] + CMDP[28 + tid] + CMDP[42 + tid];
    __syncthreads();
    if (tid < 64) {
        const int d = tid;
        float s4[4] = { s14[0], s14[1], s14[2], s14[3] };
        float gc[4][4];
        gc[0][0] = s14[4];
        gc[0][1] = gc[1][0] = s14[5];
        gc[0][2] = gc[2][0] = s14[6];
        gc[0][3] = gc[3][0] = s14[7];
        gc[1][1] = s14[8];
        gc[1][2] = gc[2][1] = s14[9];
        gc[1][3] = gc[3][1] = s14[10];
        gc[2][2] = s14[11];
        gc[2][3] = gc[3][2] = s14[12];
        gc[3][3] = s14[13];
        float wq[4];
#pragma unroll
        for (int c = 0; c < 4; ++c) wq[c] = Wq[d * 4 + c];
        const float invB = 1.0f / 65536.0f;
        float mQ = (wq[0]*s4[0] + wq[1]*s4[1] + wq[2]*s4[2] + wq[3]*s4[3]) * invB;
        float eq2 = 0.f;
#pragma unroll
        for (int c = 0; c < 4; ++c)
#pragma unroll
            for (int c2 = 0; c2 < 4; ++c2) eq2 += wq[c] * wq[c2] * gc[c][c2];
        eq2 *= invB;
        float vQ  = eq2 - mQ * mQ;
        float aQ  = gQ[d] / sqrtf(vQ + EPSV);
        float bQv = bQ[d] - mQ * aQ;
        float S2 = 0.f, S1 = 0.f;
#pragma unroll
        for (int f = 0; f < 32; ++f) { S2 += T[f * 64 + d]; S1 += U[f * 64 + d]; }
        const float invBF = 1.0f / (65536.0f * 32.0f);
        float e2 = S2 * invBF, mK = S1 * invBF;
        float vK = e2 - mK * mK;
        float aK = gK[d] / sqrtf(vK + EPSV);
        float c1 = aQ * aK * 0.125f;          // 1/sqrt(64) folded in
        C0l[d] = bQv * aK * 0.125f;
#pragma unroll
        for (int c = 0; c < 4; ++c) W2l[d * 4 + c] = c1 * wq[c];
    }
    __syncthreads();

    const int blk = blockIdx.x;               // 192
    const int h = blk / 96, rr = blk % 96;
    const int k = tid;
    float s = 0.f;
    if (rr < 80) {
        const int c = rr >> 4, fl = rr & 15;
        const float* Wsrc = (h ? Wkh : Wkz) + (size_t)fl * 64 * 256;
        for (int d = 0; d < 64; ++d) {
            float coef = (c == 0) ? C0l[d] : W2l[d * 4 + (c - 1)];
            s = fmaf(coef, Wsrc[d * 256 + k], s);
        }
    }
    // fragment-order store: chunk (h*3+nt, ks), offset (hi*32+n32)*8 + e
    const int nt = rr >> 5, n32 = rr & 31;
    const int ks = k >> 4, hi = (k >> 3) & 1, e = k & 7;
    WKFT[(size_t)((h * 3 + nt) * 16 + ks) * 512 + (hi * 32 + n32) * 8 + e] = (__bf16)s;
}

// ---------------------------------------------------------------------------
// fused_attn v5: 512 blocks x 256 threads; wave = 32 rows; NO barriers.
// B-fragments streamed from pre-transposed WKFT/WVT (coalesced dwordx4,
// L1/L2-resident). Per-wave WGT strip in LDS for intra-wave weight exchange.
__global__ __launch_bounds__(256, 2) void fused_attn(
        const float* __restrict__ feat, const float* __restrict__ hid,
        const float4* __restrict__ cmd, const __bf16* __restrict__ WVT,
        const __bf16* __restrict__ WKFT, float* __restrict__ out)
{
    __shared__ __bf16 WGTs[2048];             // [f 0..15][128 rows] 4 KiB
    const int tid  = threadIdx.x;
    const int wid  = tid >> 6, lane = tid & 63;
    const int l5   = lane & 31, hi = lane >> 5;
    const int fl   = l5 & 15;
    const bool low = (l5 < 16);
    const int wrow = (blockIdx.x << 7) + (wid << 5);   // wave's 32 rows

    float l_i[16];
    f32x16 s_acc[2];
#pragma unroll
    for (int r = 0; r < 16; ++r) { l_i[r] = 0.f; s_acc[0][r] = 0.f; s_acc[1][r] = 0.f; }

    for (int h = 0; h < 2; ++h) {
        const float* X = h ? hid : feat;

        // ---- A fragments (32x32x16): row wrow+l5, k = u*16 + hi*8 + j ----
        bf16x8 a2[16];
#pragma unroll
        for (int u = 0; u < 16; ++u) {
            const float* p = X + ((size_t)(wrow + l5) << 8) + u * 16 + hi * 8;
            float4 x0 = *(const float4*)p;
            float4 x1 = *(const float4*)(p + 4);
            a2[u] = (bf16x8){ (__bf16)x0.x, (__bf16)x0.y, (__bf16)x0.z, (__bf16)x0.w,
                              (__bf16)x1.x, (__bf16)x1.y, (__bf16)x1.z, (__bf16)x1.w };
        }

        // ---- phase 1: scores vs folded K weights (global B-frags) ----
        f32x16 acc1[3];
#pragma unroll
        for (int nt = 0; nt < 3; ++nt)
#pragma unroll
            for (int r = 0; r < 16; ++r) acc1[nt][r] = 0.f;
#pragma unroll
        for (int ks = 0; ks < 16; ++ks)
#pragma unroll
            for (int nt = 0; nt < 3; ++nt) {
                bf16x8 b = *(const bf16x8*)(WKFT
                        + (size_t)((h * 3 + nt) * 16 + ks) * 512 + lane * 8);
                acc1[nt] = MFMA32(a2[ks], b, acc1[nt]);
            }

        // epilogue: combine c-terms, exp, store wgt, accumulate l
#pragma unroll
        for (int g = 0; g < 4; ++g) {
            bf16x4 wv4;
#pragma unroll
            for (int j = 0; j < 4; ++j) {
                const int r = g * 4 + j;
                const int row32 = j + 8 * g + 4 * hi;
                float4 cm = cmd[wrow + row32];
                float e0, e1, t0[3], t1[3];
#pragma unroll
                for (int nt = 0; nt < 3; ++nt) {
                    e0 = acc1[nt][r];
                    e1 = __shfl_xor(e0, 16);
                    t0[nt] = low ? e0 : e1;
                    t1[nt] = low ? e1 : e0;
                }
                float sc = t0[0] + cm.x * t1[0] + cm.y * t0[1]
                                 + cm.z * t1[1] + cm.w * t0[2];
                float w = __expf(sc);
                wv4[j] = (__bf16)w;
                float ws = w;
                ws += __shfl_xor(ws, 1); ws += __shfl_xor(ws, 2);
                ws += __shfl_xor(ws, 4); ws += __shfl_xor(ws, 8);
                l_i[r] += ws;
            }
            if (low) *(bf16x4*)&WGTs[fl * 128 + (wid << 5) + 8 * g + 4 * hi] = wv4;
        }

        // ---- phase 2: weighted V accumulation (global B-frags) ----
#pragma unroll 2
        for (int f2 = 0; f2 < 16; ++f2) {
            const int f = h * 16 + f2;
            f32x16 acc2[2];
#pragma unroll
            for (int r = 0; r < 16; ++r) { acc2[0][r] = 0.f; acc2[1][r] = 0.f; }
#pragma unroll
            for (int ks = 0; ks < 16; ++ks)
#pragma unroll
                for (int nt = 0; nt < 2; ++nt) {
                    bf16x8 b = *(const bf16x8*)(WVT
                            + (size_t)((f * 2 + nt) * 16 + ks) * 512 + lane * 8);
                    acc2[nt] = MFMA32(a2[ks], b, acc2[nt]);
                }
#pragma unroll
            for (int g = 0; g < 4; ++g) {
                bf16x4 wv = *(const bf16x4*)&WGTs[f2 * 128 + (wid << 5) + 8 * g + 4 * hi];
#pragma unroll
                for (int j = 0; j < 4; ++j) {
                    float w = (float)wv[j];
                    s_acc[0][g * 4 + j] += w * acc2[0][g * 4 + j];
                    s_acc[1][g * 4 + j] += w * acc2[1][g * 4 + j];
                }
            }
        }
    }

    // ---- epilogue: divide by l, store ----
#pragma unroll
    for (int g = 0; g < 4; ++g)
#pragma unroll
        for (int j = 0; j < 4; ++j) {
            const int r = g * 4 + j;
            float inv = 1.0f / l_i[r];
            size_t row = (size_t)(wrow + j + 8 * g + 4 * hi);
            out[(row << 6) + l5]      = s_acc[0][r] * inv;
            out[(row << 6) + 32 + l5] = s_acc[1][r] * inv;
        }
}

// ---------------------------------------------------------------------------
extern "C" void kernel_launch(void* const* d_in, const int* in_sizes, int n_in,
                              void* d_out, int out_size, void* d_ws, size_t ws_size,
                              hipStream_t stream)
{
    (void)in_sizes; (void)n_in; (void)out_size; (void)ws_size;
    const float* feature = (const float*)d_in[0];
    const float* hidden  = (const float*)d_in[1];
    const float* command = (const float*)d_in[2];
    const float* Wq      = (const float*)d_in[3];
    const float* Wkz     = (const float*)d_in[4];
    const float* Wkh     = (const float*)d_in[5];
    const float* Wvz     = (const float*)d_in[6];
    const float* Wvh     = (const float*)d_in[7];
    const float* gammaQ  = (const float*)d_in[8];
    const float* betaQ   = (const float*)d_in[9];
    const float* gammaK  = (const float*)d_in[10];
    const float* betaK   = (const float*)d_in[11];

    char* ws = (char*)d_ws;
    __bf16* WVT  = (__bf16*)(ws + WS_WVT);
    __bf16* WKFT = (__bf16*)(ws + WS_WKFT);
    float*  G    = (float*)(ws + WS_G);
    float*  CS   = (float*)(ws + WS_CS);
    float*  CMDP = (float*)(ws + WS_CMDP);
    float*  Tj   = (float*)(ws + WS_T);
    float*  Uj   = (float*)(ws + WS_U);
    float*  outp = (float*)d_out;
    __bf16* Gp   = (__bf16*)d_out;            // 16.78 MB scratch = 128 bf16 partials

    hipMemsetAsync(ws + WS_CS, 0, 0x800, stream);
    setup1<<<164, 1024, 0, stream>>>(feature, hidden, (const float4*)command,
                                     Wvz, Wvh, WVT, CMDP, CS, Gp);
    gram_reduce<<<512, 256, 0, stream>>>(Gp, G);
    rowstats<<<256, 256, 0, stream>>>(Wkz, Wkh, G, CS, Tj, Uj);
    foldK2<<<192, 256, 0, stream>>>(Wkz, Wkh, Wq, gammaQ, betaQ, gammaK, betaK,
                                    CMDP, Tj, Uj, WKFT);
    fused_attn<<<512, 256, 0, stream>>>(feature, hidden, (const float4*)command,
                                        WVT, WKFT, outp);
}